// Round 7
// baseline (890.003 us; speedup 1.0000x reference)
//
#include <hip/hip_runtime.h>

#define H   128
#define TM  64

// bf16 round-to-nearest-even of fp32, returns low 16 bits
__device__ __forceinline__ unsigned int bfr(float f) {
  unsigned int u = __float_as_uint(f);
  return (u + 0x7fffu + ((u >> 16) & 1u)) >> 16;
}
__device__ __forceinline__ float bf_lo(unsigned int d) {  // low half -> f32
  return __uint_as_float(d << 16);
}
__device__ __forceinline__ float bf_hi(unsigned int d) {  // high half -> f32
  return __uint_as_float(d & 0xffff0000u);
}

// ---------------- node encoder: h2 = bf16(x @ node_w + node_b) -------------
__global__ __launch_bounds__(128) void node_enc(const float* __restrict__ x,
    const float* __restrict__ w, const float* __restrict__ b,
    unsigned int* __restrict__ h2, int N) {
  int row = blockIdx.x;
  if (row >= N) return;
  int j = threadIdx.x;
  __shared__ float xs[64];
  if (j < 64) xs[j] = x[(size_t)row * 64 + j];
  __syncthreads();
  float acc = b[j];
#pragma unroll
  for (int k = 0; k < 64; ++k) acc = fmaf(xs[k], w[k * H + j], acc);
  float part = __shfl_down(acc, 1, 64);
  if ((j & 1) == 0) {
    unsigned int d = bfr(acc) | (bfr(part) << 16);
    h2[(size_t)row * 64 + (j >> 1)] = d;
  }
}

// ---------------- CSR build: degree count ----------------------------------
__global__ __launch_bounds__(256) void count_deg(const int* __restrict__ dst,
    int* __restrict__ cnt, int E) {
  int e = blockIdx.x * 256 + threadIdx.x;
  if (e < E) atomicAdd(&cnt[dst[e]], 1);
}

// ---------------- scan pass 1: per-block (256-elem) sums -------------------
__global__ __launch_bounds__(256) void block_sum(const int* __restrict__ cnt,
    int* __restrict__ bsum, int N) {
  int t = threadIdx.x;
  int i = blockIdx.x * 256 + t;
  int v = (i < N) ? cnt[i] : 0;
#pragma unroll
  for (int o = 32; o > 0; o >>= 1) v += __shfl_down(v, o, 64);
  __shared__ int wt[4];
  if ((t & 63) == 0) wt[t >> 6] = v;
  __syncthreads();
  if (t == 0) bsum[blockIdx.x] = wt[0] + wt[1] + wt[2] + wt[3];
}

// ---------------- scan pass 2: 1-block scan of block sums (nb <= 1024) -----
__global__ __launch_bounds__(1024) void scan_bsum(const int* __restrict__ bsum,
    int* __restrict__ bbase, int nb) {
  __shared__ int s[1024];
  int t = threadIdx.x;
  int v = (t < nb) ? bsum[t] : 0;
  s[t] = v;
  __syncthreads();
  for (int o = 1; o < 1024; o <<= 1) {
    int u = (t >= o) ? s[t - o] : 0;
    __syncthreads();
    s[t] += u;
    __syncthreads();
  }
  if (t < nb) bbase[t] = s[t] - v;  // exclusive
}

// ---------------- scan pass 3: in-block scan + base -> off, cursor ---------
__global__ __launch_bounds__(256) void scan_pass(const int* __restrict__ cnt,
    const int* __restrict__ bbase, int* __restrict__ off,
    int* __restrict__ cursor, int N) {
  int t = threadIdx.x;
  int i = blockIdx.x * 256 + t;
  int v = (i < N) ? cnt[i] : 0;
  int lane = t & 63;
  int incl = v;
#pragma unroll
  for (int o = 1; o < 64; o <<= 1) {
    int u = __shfl_up(incl, o, 64);
    if (lane >= o) incl += u;
  }
  __shared__ int wtot[4];
  int w = t >> 6;
  if (lane == 63) wtot[w] = incl;
  __syncthreads();
  if (t == 0) {
    int run = 0;
#pragma unroll
    for (int k = 0; k < 4; ++k) { int tmp = wtot[k]; wtot[k] = run; run += tmp; }
  }
  __syncthreads();
  int excl = incl - v + wtot[w] + bbase[blockIdx.x];
  if (i < N) { off[i] = excl; cursor[i] = excl; }
  if (i == N - 1) off[N] = excl + v;
}

// ---------------- CSR build: scatter edge ids into buckets -----------------
__global__ __launch_bounds__(256) void scatter_csr(const int* __restrict__ src,
    const int* __restrict__ dst, int* __restrict__ cursor,
    int* __restrict__ perm, int* __restrict__ src_perm, int E) {
  int e = blockIdx.x * 256 + threadIdx.x;
  if (e < E) {
    int pos = atomicAdd(&cursor[dst[e]], 1);
    perm[pos] = e;
    src_perm[pos] = src[e];
  }
}

// ---------------- pack edge_attr rows into permuted bf16 stream ------------
__global__ __launch_bounds__(256) void pack_ea(const float* __restrict__ ea,
    const int* __restrict__ perm, unsigned int* __restrict__ eap, int E) {
  int i = blockIdx.x * 256 + threadIdx.x;
  if (i >= E) return;
  const float4* a = (const float4*)(ea + (size_t)perm[i] * 16);
  unsigned int o[8];
#pragma unroll
  for (int q = 0; q < 4; ++q) {
    float4 v = a[q];
    o[2 * q]     = bfr(v.x) | (bfr(v.y) << 16);
    o[2 * q + 1] = bfr(v.z) | (bfr(v.w) << 16);
  }
  uint4* d = (uint4*)(eap + (size_t)i * 8);
  d[0] = make_uint4(o[0], o[1], o[2], o[3]);
  d[1] = make_uint4(o[4], o[5], o[6], o[7]);
}

// ---- CSR aggregation: z[n] = h[n] + sum_{e->n} relu(h[src]+ea[e]@ew+eb) ---
// Wave-per-node. h gathered as packed bf16 (256 B/edge). ea is a sequential
// permuted bf16 scalar stream (32 B/edge, SMEM pipe + SALU unpack).
// 4-edge unroll keeps 4 gathers in flight. No LDS, no barriers.
__global__ __launch_bounds__(256) void aggr_csr(
    const unsigned int* __restrict__ eap, const float* __restrict__ ew,
    const float* __restrict__ eb, const int* __restrict__ src_perm,
    const int* __restrict__ off, const unsigned int* __restrict__ h2,
    float* __restrict__ z, int N) {
  int wid = threadIdx.x >> 6;
  int lane = threadIdx.x & 63;
  int n = blockIdx.x * 4 + wid;
  if (n >= N) return;
  int beg = off[n], end = off[n + 1];
  int c = lane * 2;
  float2 wc[16];
#pragma unroll
  for (int k = 0; k < 16; ++k) wc[k] = *(const float2*)&ew[k * H + c];
  float2 bias = *(const float2*)&eb[c];
  float ax = 0.f, ay = 0.f;
  int i = beg;
  for (; i + 4 <= end; i += 4) {
    int s0 = __builtin_amdgcn_readfirstlane(src_perm[i]);
    int s1 = __builtin_amdgcn_readfirstlane(src_perm[i + 1]);
    int s2 = __builtin_amdgcn_readfirstlane(src_perm[i + 2]);
    int s3 = __builtin_amdgcn_readfirstlane(src_perm[i + 3]);
    unsigned int hv0 = h2[(size_t)s0 * 64 + lane];
    unsigned int hv1 = h2[(size_t)s1 * 64 + lane];
    unsigned int hv2 = h2[(size_t)s2 * 64 + lane];
    unsigned int hv3 = h2[(size_t)s3 * 64 + lane];
    const unsigned int* a0 = eap + (size_t)i * 8;
    float x0 = bias.x, y0 = bias.y, x1 = bias.x, y1 = bias.y;
    float x2 = bias.x, y2 = bias.y, x3 = bias.x, y3 = bias.y;
#pragma unroll
    for (int k2 = 0; k2 < 8; ++k2) {
      unsigned int d0 = a0[k2];
      unsigned int d1 = a0[8 + k2];
      unsigned int d2 = a0[16 + k2];
      unsigned int d3 = a0[24 + k2];
      float e0 = bf_lo(d0), o0 = bf_hi(d0);
      float e1 = bf_lo(d1), o1 = bf_hi(d1);
      float e2 = bf_lo(d2), o2 = bf_hi(d2);
      float e3 = bf_lo(d3), o3 = bf_hi(d3);
      float2 we = wc[2 * k2], wo = wc[2 * k2 + 1];
      x0 = fmaf(e0, we.x, x0); y0 = fmaf(e0, we.y, y0);
      x0 = fmaf(o0, wo.x, x0); y0 = fmaf(o0, wo.y, y0);
      x1 = fmaf(e1, we.x, x1); y1 = fmaf(e1, we.y, y1);
      x1 = fmaf(o1, wo.x, x1); y1 = fmaf(o1, wo.y, y1);
      x2 = fmaf(e2, we.x, x2); y2 = fmaf(e2, we.y, y2);
      x2 = fmaf(o2, wo.x, x2); y2 = fmaf(o2, wo.y, y2);
      x3 = fmaf(e3, we.x, x3); y3 = fmaf(e3, we.y, y3);
      x3 = fmaf(o3, wo.x, x3); y3 = fmaf(o3, wo.y, y3);
    }
    ax += fmaxf(x0 + bf_lo(hv0), 0.f) + fmaxf(x1 + bf_lo(hv1), 0.f) +
          fmaxf(x2 + bf_lo(hv2), 0.f) + fmaxf(x3 + bf_lo(hv3), 0.f);
    ay += fmaxf(y0 + bf_hi(hv0), 0.f) + fmaxf(y1 + bf_hi(hv1), 0.f) +
          fmaxf(y2 + bf_hi(hv2), 0.f) + fmaxf(y3 + bf_hi(hv3), 0.f);
  }
  for (; i < end; ++i) {
    int s0 = __builtin_amdgcn_readfirstlane(src_perm[i]);
    unsigned int hv0 = h2[(size_t)s0 * 64 + lane];
    const unsigned int* a0 = eap + (size_t)i * 8;
    float x0 = bias.x, y0 = bias.y;
#pragma unroll
    for (int k2 = 0; k2 < 8; ++k2) {
      unsigned int d0 = a0[k2];
      float e0 = bf_lo(d0), o0 = bf_hi(d0);
      float2 we = wc[2 * k2], wo = wc[2 * k2 + 1];
      x0 = fmaf(e0, we.x, x0); y0 = fmaf(e0, we.y, y0);
      x0 = fmaf(o0, wo.x, x0); y0 = fmaf(o0, wo.y, y0);
    }
    ax += fmaxf(x0 + bf_lo(hv0), 0.f);
    ay += fmaxf(y0 + bf_hi(hv0), 0.f);
  }
  unsigned int hn = h2[(size_t)n * 64 + lane];
  *(float2*)&z[(size_t)n * H + c] = make_float2(bf_lo(hn) + ax, bf_hi(hn) + ay);
}

// ---- GEMM1: t = z @ w1 + b1, 64x128 tile, 8r x 4c per thread --------------
__global__ __launch_bounds__(256) void mlp1(const float* __restrict__ zin,
    const float* __restrict__ w1, const float* __restrict__ b1,
    float* __restrict__ tout, float* __restrict__ sum,
    float* __restrict__ sumsq, int N) {
  int r0 = blockIdx.x * TM;
  int tid = threadIdx.x;
  int cl = tid & 31;
  int rg = tid >> 5;
  int c0 = cl * 4;
  __shared__ float z[TM][H];
  const float4* zin4 = (const float4*)zin;
#pragma unroll
  for (int f = 0; f < 8; ++f) {
    int q = f * 256 + tid;
    int row = q >> 5, col4 = q & 31;
    int g = r0 + row;
    float4 v = make_float4(0.f, 0.f, 0.f, 0.f);
    if (g < N) v = zin4[(size_t)g * 32 + col4];
    *(float4*)&z[row][col4 * 4] = v;
  }
  __syncthreads();
  float4 bv = *(const float4*)&b1[c0];
  float acc[8][4];
#pragma unroll
  for (int r = 0; r < 8; ++r) {
    acc[r][0] = bv.x; acc[r][1] = bv.y; acc[r][2] = bv.z; acc[r][3] = bv.w;
  }
  int zr = rg * 8;
#pragma unroll 4
  for (int k4 = 0; k4 < 32; ++k4) {
    float4 wa = *(const float4*)&w1[(k4 * 4 + 0) * H + c0];
    float4 wb = *(const float4*)&w1[(k4 * 4 + 1) * H + c0];
    float4 wc = *(const float4*)&w1[(k4 * 4 + 2) * H + c0];
    float4 wd = *(const float4*)&w1[(k4 * 4 + 3) * H + c0];
#pragma unroll
    for (int r = 0; r < 8; ++r) {
      float4 zv = *(const float4*)&z[zr + r][k4 * 4];
      acc[r][0] = fmaf(zv.x, wa.x, acc[r][0]);
      acc[r][1] = fmaf(zv.x, wa.y, acc[r][1]);
      acc[r][2] = fmaf(zv.x, wa.z, acc[r][2]);
      acc[r][3] = fmaf(zv.x, wa.w, acc[r][3]);
      acc[r][0] = fmaf(zv.y, wb.x, acc[r][0]);
      acc[r][1] = fmaf(zv.y, wb.y, acc[r][1]);
      acc[r][2] = fmaf(zv.y, wb.z, acc[r][2]);
      acc[r][3] = fmaf(zv.y, wb.w, acc[r][3]);
      acc[r][0] = fmaf(zv.z, wc.x, acc[r][0]);
      acc[r][1] = fmaf(zv.z, wc.y, acc[r][1]);
      acc[r][2] = fmaf(zv.z, wc.z, acc[r][2]);
      acc[r][3] = fmaf(zv.z, wc.w, acc[r][3]);
      acc[r][0] = fmaf(zv.w, wd.x, acc[r][0]);
      acc[r][1] = fmaf(zv.w, wd.y, acc[r][1]);
      acc[r][2] = fmaf(zv.w, wd.z, acc[r][2]);
      acc[r][3] = fmaf(zv.w, wd.w, acc[r][3]);
    }
  }
  float s1[4] = {0.f, 0.f, 0.f, 0.f}, s2[4] = {0.f, 0.f, 0.f, 0.f};
#pragma unroll
  for (int r = 0; r < 8; ++r) {
    int g = r0 + zr + r;
    if (g < N) {
      *(float4*)&tout[(size_t)g * H + c0] =
          make_float4(acc[r][0], acc[r][1], acc[r][2], acc[r][3]);
#pragma unroll
      for (int c = 0; c < 4; ++c) {
        s1[c] += acc[r][c];
        s2[c] += acc[r][c] * acc[r][c];
      }
    }
  }
  __syncthreads();
  float* red = &z[0][0];
#pragma unroll
  for (int c = 0; c < 4; ++c) {
    red[rg * H + c0 + c] = s1[c];
    red[1024 + rg * H + c0 + c] = s2[c];
  }
  __syncthreads();
  if (tid < H) {
    float a = 0.f, b = 0.f;
#pragma unroll
    for (int g = 0; g < 8; ++g) {
      a += red[g * H + tid];
      b += red[1024 + g * H + tid];
    }
    atomicAdd(&sum[tid], a);
    atomicAdd(&sumsq[tid], b);
  }
}

// ---- BN finalize ----------------------------------------------------------
__global__ void bn_finalize(const float* __restrict__ sum,
    const float* __restrict__ sumsq, const float* __restrict__ g,
    const float* __restrict__ beta, float* __restrict__ scale,
    float* __restrict__ shift, float invN) {
  int j = threadIdx.x;
  float mu = sum[j] * invN;
  float var = sumsq[j] * invN - mu * mu;
  float inv = rsqrtf(var + 1e-5f);
  float sc = g[j] * inv;
  scale[j] = sc;
  shift[j] = beta[j] - mu * sc;
}

// ---- GEMM2: h2 = bf16(relu( relu(t*sc+sh) @ w2 + b2 )), fused pool last ---
__global__ __launch_bounds__(256) void mlp2(const float* __restrict__ tin,
    const float* __restrict__ scale, const float* __restrict__ shift,
    const float* __restrict__ w2, const float* __restrict__ b2,
    unsigned int* __restrict__ h2out, int N,
    const int* __restrict__ batch, float* __restrict__ pooled) {
  int r0 = blockIdx.x * TM;
  int tid = threadIdx.x;
  int cl = tid & 31;
  int rg = tid >> 5;
  int c0 = cl * 4;
  __shared__ float z[TM][H];
  const float4* tin4 = (const float4*)tin;
#pragma unroll
  for (int f = 0; f < 8; ++f) {
    int q = f * 256 + tid;
    int row = q >> 5, col4 = q & 31;
    int g = r0 + row;
    float4 v = make_float4(0.f, 0.f, 0.f, 0.f);
    if (g < N) {
      v = tin4[(size_t)g * 32 + col4];
      float4 sc = *(const float4*)&scale[col4 * 4];
      float4 sh = *(const float4*)&shift[col4 * 4];
      v.x = fmaxf(fmaf(v.x, sc.x, sh.x), 0.f);
      v.y = fmaxf(fmaf(v.y, sc.y, sh.y), 0.f);
      v.z = fmaxf(fmaf(v.z, sc.z, sh.z), 0.f);
      v.w = fmaxf(fmaf(v.w, sc.w, sh.w), 0.f);
    }
    *(float4*)&z[row][col4 * 4] = v;
  }
  __syncthreads();
  float4 bv = *(const float4*)&b2[c0];
  float acc[8][4];
#pragma unroll
  for (int r = 0; r < 8; ++r) {
    acc[r][0] = bv.x; acc[r][1] = bv.y; acc[r][2] = bv.z; acc[r][3] = bv.w;
  }
  int zr = rg * 8;
#pragma unroll 4
  for (int k4 = 0; k4 < 32; ++k4) {
    float4 wa = *(const float4*)&w2[(k4 * 4 + 0) * H + c0];
    float4 wb = *(const float4*)&w2[(k4 * 4 + 1) * H + c0];
    float4 wc = *(const float4*)&w2[(k4 * 4 + 2) * H + c0];
    float4 wd = *(const float4*)&w2[(k4 * 4 + 3) * H + c0];
#pragma unroll
    for (int r = 0; r < 8; ++r) {
      float4 zv = *(const float4*)&z[zr + r][k4 * 4];
      acc[r][0] = fmaf(zv.x, wa.x, acc[r][0]);
      acc[r][1] = fmaf(zv.x, wa.y, acc[r][1]);
      acc[r][2] = fmaf(zv.x, wa.z, acc[r][2]);
      acc[r][3] = fmaf(zv.x, wa.w, acc[r][3]);
      acc[r][0] = fmaf(zv.y, wb.x, acc[r][0]);
      acc[r][1] = fmaf(zv.y, wb.y, acc[r][1]);
      acc[r][2] = fmaf(zv.y, wb.z, acc[r][2]);
      acc[r][3] = fmaf(zv.y, wb.w, acc[r][3]);
      acc[r][0] = fmaf(zv.z, wc.x, acc[r][0]);
      acc[r][1] = fmaf(zv.z, wc.y, acc[r][1]);
      acc[r][2] = fmaf(zv.z, wc.z, acc[r][2]);
      acc[r][3] = fmaf(zv.z, wc.w, acc[r][3]);
      acc[r][0] = fmaf(zv.w, wd.x, acc[r][0]);
      acc[r][1] = fmaf(zv.w, wd.y, acc[r][1]);
      acc[r][2] = fmaf(zv.w, wd.z, acc[r][2]);
      acc[r][3] = fmaf(zv.w, wd.w, acc[r][3]);
    }
  }
#pragma unroll
  for (int r = 0; r < 8; ++r) {
#pragma unroll
    for (int c = 0; c < 4; ++c) acc[r][c] = fmaxf(acc[r][c], 0.f);
  }
  if (h2out != nullptr) {
#pragma unroll
    for (int r = 0; r < 8; ++r) {
      int g = r0 + zr + r;
      if (g < N) {
        unsigned int d0 = bfr(acc[r][0]) | (bfr(acc[r][1]) << 16);
        unsigned int d1 = bfr(acc[r][2]) | (bfr(acc[r][3]) << 16);
        *(uint2*)&h2out[(size_t)g * 64 + (c0 >> 1)] = make_uint2(d0, d1);
      }
    }
  }
  if (pooled != nullptr) {
    int gbase = r0 + zr;
    if (gbase < N) {
      int cur = batch[gbase];
      float pa[4] = {0.f, 0.f, 0.f, 0.f};
      for (int r = 0; r < 8; ++r) {
        int g = gbase + r;
        if (g >= N) break;
        int bb = batch[g];
        if (bb != cur) {
#pragma unroll
          for (int c = 0; c < 4; ++c)
            atomicAdd(&pooled[(size_t)cur * H + c0 + c], pa[c]);
          pa[0] = pa[1] = pa[2] = pa[3] = 0.f;
          cur = bb;
        }
#pragma unroll
        for (int c = 0; c < 4; ++c) pa[c] += acc[r][c];
      }
#pragma unroll
      for (int c = 0; c < 4; ++c)
        atomicAdd(&pooled[(size_t)cur * H + c0 + c], pa[c]);
    }
  }
}

// ---- final FC: out = pooled @ fc_w + fc_b ---------------------------------
__global__ __launch_bounds__(128) void fc_kernel(const float* __restrict__ pooled,
    const float* __restrict__ w, const float* __restrict__ b,
    float* __restrict__ out, int C) {
  int g = blockIdx.x;
  int j = threadIdx.x;
  __shared__ float p[H];
  p[j] = pooled[(size_t)g * H + j];
  __syncthreads();
  if (j < C) {
    float acc = b[j];
#pragma unroll 4
    for (int k = 0; k < H; ++k) acc = fmaf(p[k], w[k * C + j], acc);
    out[(size_t)g * C + j] = acc;
  }
}

extern "C" void kernel_launch(void* const* d_in, const int* in_sizes, int n_in,
                              void* d_out, int out_size, void* d_ws, size_t ws_size,
                              hipStream_t stream) {
  const float* x         = (const float*)d_in[0];
  const float* edge_attr = (const float*)d_in[1];
  const float* node_w    = (const float*)d_in[2];
  const float* node_b    = (const float*)d_in[3];
  const float* edge_w    = (const float*)d_in[4];
  const float* edge_b    = (const float*)d_in[5];
  const float* lin1_w    = (const float*)d_in[6];
  const float* lin1_b    = (const float*)d_in[7];
  const float* bn_g      = (const float*)d_in[8];
  const float* bn_b      = (const float*)d_in[9];
  const float* lin2_w    = (const float*)d_in[10];
  const float* lin2_b    = (const float*)d_in[11];
  const float* fc_w      = (const float*)d_in[12];
  const float* fc_b      = (const float*)d_in[13];
  const int*   edge_index= (const int*)d_in[14];
  const int*   batch     = (const int*)d_in[15];

  int N = in_sizes[0] / 64;       // 50000
  int E = in_sizes[1] / 16;       // 640000
  int C = in_sizes[13];           // 10
  int G = out_size / C;           // 512

  const int* src = edge_index;
  const int* dst = edge_index + E;

  float* ws     = (float*)d_ws;
  float* zt     = ws;                        // [N,H] z and t aliased in-place
  float* pooled = zt + (size_t)N * H;        // [G,H]
  float* sums   = pooled + (size_t)G * H;    // [H]
  float* sumsq  = sums + H;                  // [H]
  float* scale  = sumsq + H;                 // [H]
  float* shift  = scale + H;                 // [H]
  unsigned int* h2 = (unsigned int*)(shift + H);  // [N,64] packed bf16
  int*   cnt      = (int*)(h2 + (size_t)N * 64);  // [N]
  int*   off      = cnt + N;                 // [N+1]
  int*   cursor   = off + N + 1;             // [N]
  int*   src_perm = cursor + N;              // [E]
  int*   perm     = src_perm + E;            // [E]
  unsigned int* eap = (unsigned int*)(perm + E);  // [E,8] packed bf16 perm'd
  int*   bsum     = (int*)(eap + (size_t)E * 8);  // [nb]
  int*   bbase    = bsum + 1024;             // [nb]

  int nb = (N + 255) / 256;                  // 196 <= 1024

  // --- CSR build + edge-attr pack (every launch; deterministic) ---
  hipMemsetAsync(cnt, 0, (size_t)N * sizeof(int), stream);
  count_deg<<<(E + 255) / 256, 256, 0, stream>>>(dst, cnt, E);
  block_sum<<<nb, 256, 0, stream>>>(cnt, bsum, N);
  scan_bsum<<<1, 1024, 0, stream>>>(bsum, bbase, nb);
  scan_pass<<<nb, 256, 0, stream>>>(cnt, bbase, off, cursor, N);
  scatter_csr<<<(E + 255) / 256, 256, 0, stream>>>(src, dst, cursor, perm, src_perm, E);
  pack_ea<<<(E + 255) / 256, 256, 0, stream>>>(edge_attr, perm, eap, E);

  node_enc<<<N, 128, 0, stream>>>(x, node_w, node_b, h2, N);

  int mblk = (N + TM - 1) / TM;
  int ablk = (N + 3) / 4;
  for (int l = 0; l < 3; ++l) {
    hipMemsetAsync(sums, 0, 2 * H * sizeof(float), stream);
    aggr_csr<<<ablk, 256, 0, stream>>>(eap, edge_w, edge_b, src_perm,
                                       off, h2, zt, N);
    mlp1<<<mblk, 256, 0, stream>>>(zt, lin1_w + (size_t)l * H * H,
                                   lin1_b + (size_t)l * H, zt, sums, sumsq, N);
    bn_finalize<<<1, H, 0, stream>>>(sums, sumsq, bn_g + (size_t)l * H,
                                     bn_b + (size_t)l * H, scale, shift, 1.0f / N);
    bool last = (l == 2);
    if (last) hipMemsetAsync(pooled, 0, (size_t)G * H * sizeof(float), stream);
    mlp2<<<mblk, 256, 0, stream>>>(zt, scale, shift, lin2_w + (size_t)l * H * H,
                                   lin2_b + (size_t)l * H,
                                   last ? nullptr : h2, N,
                                   batch, last ? pooled : nullptr);
  }

  fc_kernel<<<G, 128, 0, stream>>>(pooled, fc_w, fc_b, (float*)d_out, C);
}

// Round 8
// 855.270 us; speedup vs baseline: 1.0406x; 1.0406x over previous
//
#include <hip/hip_runtime.h>

#define H   128
#define TM  64

// bf16 round-to-nearest-even of fp32, returns low 16 bits
__device__ __forceinline__ unsigned int bfr(float f) {
  unsigned int u = __float_as_uint(f);
  return (u + 0x7fffu + ((u >> 16) & 1u)) >> 16;
}
__device__ __forceinline__ float bf_lo(unsigned int d) {
  return __uint_as_float(d << 16);
}
__device__ __forceinline__ float bf_hi(unsigned int d) {
  return __uint_as_float(d & 0xffff0000u);
}

// ---------------- node encoder: h2 = bf16(x @ node_w + node_b) -------------
__global__ __launch_bounds__(128) void node_enc(const float* __restrict__ x,
    const float* __restrict__ w, const float* __restrict__ b,
    unsigned int* __restrict__ h2, int N) {
  int row = blockIdx.x;
  if (row >= N) return;
  int j = threadIdx.x;
  __shared__ float xs[64];
  if (j < 64) xs[j] = x[(size_t)row * 64 + j];
  __syncthreads();
  float acc = b[j];
#pragma unroll
  for (int k = 0; k < 64; ++k) acc = fmaf(xs[k], w[k * H + j], acc);
  float part = __shfl_down(acc, 1, 64);
  if ((j & 1) == 0) {
    unsigned int d = bfr(acc) | (bfr(part) << 16);
    h2[(size_t)row * 64 + (j >> 1)] = d;
  }
}

// ---------------- CSR build: degree count ----------------------------------
__global__ __launch_bounds__(256) void count_deg(const int* __restrict__ dst,
    int* __restrict__ cnt, int E) {
  int e = blockIdx.x * 256 + threadIdx.x;
  if (e < E) atomicAdd(&cnt[dst[e]], 1);
}

// ---------------- scan pass 1 ----------------------------------------------
__global__ __launch_bounds__(256) void block_sum(const int* __restrict__ cnt,
    int* __restrict__ bsum, int N) {
  int t = threadIdx.x;
  int i = blockIdx.x * 256 + t;
  int v = (i < N) ? cnt[i] : 0;
#pragma unroll
  for (int o = 32; o > 0; o >>= 1) v += __shfl_down(v, o, 64);
  __shared__ int wt[4];
  if ((t & 63) == 0) wt[t >> 6] = v;
  __syncthreads();
  if (t == 0) bsum[blockIdx.x] = wt[0] + wt[1] + wt[2] + wt[3];
}

// ---------------- scan pass 2 ----------------------------------------------
__global__ __launch_bounds__(1024) void scan_bsum(const int* __restrict__ bsum,
    int* __restrict__ bbase, int nb) {
  __shared__ int s[1024];
  int t = threadIdx.x;
  int v = (t < nb) ? bsum[t] : 0;
  s[t] = v;
  __syncthreads();
  for (int o = 1; o < 1024; o <<= 1) {
    int u = (t >= o) ? s[t - o] : 0;
    __syncthreads();
    s[t] += u;
    __syncthreads();
  }
  if (t < nb) bbase[t] = s[t] - v;
}

// ---------------- scan pass 3 ----------------------------------------------
__global__ __launch_bounds__(256) void scan_pass(const int* __restrict__ cnt,
    const int* __restrict__ bbase, int* __restrict__ off,
    int* __restrict__ cursor, int N) {
  int t = threadIdx.x;
  int i = blockIdx.x * 256 + t;
  int v = (i < N) ? cnt[i] : 0;
  int lane = t & 63;
  int incl = v;
#pragma unroll
  for (int o = 1; o < 64; o <<= 1) {
    int u = __shfl_up(incl, o, 64);
    if (lane >= o) incl += u;
  }
  __shared__ int wtot[4];
  int w = t >> 6;
  if (lane == 63) wtot[w] = incl;
  __syncthreads();
  if (t == 0) {
    int run = 0;
#pragma unroll
    for (int k = 0; k < 4; ++k) { int tmp = wtot[k]; wtot[k] = run; run += tmp; }
  }
  __syncthreads();
  int excl = incl - v + wtot[w] + bbase[blockIdx.x];
  if (i < N) { off[i] = excl; cursor[i] = excl; }
  if (i == N - 1) off[N] = excl + v;
}

// ---------------- CSR build: scatter ---------------------------------------
__global__ __launch_bounds__(256) void scatter_csr(const int* __restrict__ src,
    const int* __restrict__ dst, int* __restrict__ cursor,
    int* __restrict__ perm, int* __restrict__ src_perm, int E) {
  int e = blockIdx.x * 256 + threadIdx.x;
  if (e < E) {
    int pos = atomicAdd(&cursor[dst[e]], 1);
    perm[pos] = e;
    src_perm[pos] = src[e];
  }
}

// ---- one-time edge encoder: encp[i] = bf16(ea[perm[i]] @ ew + eb) ---------
// Wave handles a contiguous chunk of permuted edges; ew held in registers,
// ea rows via wave-uniform s_loads, output is a coalesced bf16 stream.
__global__ __launch_bounds__(256) void enc_edges(const float* __restrict__ ea,
    const float* __restrict__ ew, const float* __restrict__ eb,
    const int* __restrict__ perm, unsigned int* __restrict__ encp,
    int E, int chunk) {
  int wid = threadIdx.x >> 6, lane = threadIdx.x & 63;
  int wv = blockIdx.x * 4 + wid;
  int i0 = wv * chunk;
  int i1 = min(E, i0 + chunk);
  if (i0 >= E) return;
  int c = lane * 2;
  float2 wc[16];
#pragma unroll
  for (int k = 0; k < 16; ++k) wc[k] = *(const float2*)&ew[k * H + c];
  float2 bias = *(const float2*)&eb[c];
#pragma unroll 2
  for (int i = i0; i < i1; ++i) {
    int e = __builtin_amdgcn_readfirstlane(perm[i]);
    const float* a = ea + (size_t)e * 16;
    float x = bias.x, y = bias.y;
#pragma unroll
    for (int k = 0; k < 16; ++k) {
      float ak = a[k];
      x = fmaf(ak, wc[k].x, x);
      y = fmaf(ak, wc[k].y, y);
    }
    encp[(size_t)i * 64 + lane] = bfr(x) | (bfr(y) << 16);
  }
}

// ---- aggregation (enc path): z[n] = h[n] + sum relu(h2[src] + encp[i]) ----
// Per edge: 1 sequential dword (encp) + 1 gathered dword (h2) + ~16 VALU.
__global__ __launch_bounds__(256) void aggr_enc(
    const unsigned int* __restrict__ encp, const int* __restrict__ src_perm,
    const int* __restrict__ off, const unsigned int* __restrict__ h2,
    float* __restrict__ z, int N) {
  int wid = threadIdx.x >> 6, lane = threadIdx.x & 63;
  int n = blockIdx.x * 4 + wid;
  if (n >= N) return;
  int beg = off[n], end = off[n + 1];
  float ax = 0.f, ay = 0.f;
  int i = beg;
  for (; i + 4 <= end; i += 4) {
    int s0 = __builtin_amdgcn_readfirstlane(src_perm[i]);
    int s1 = __builtin_amdgcn_readfirstlane(src_perm[i + 1]);
    int s2 = __builtin_amdgcn_readfirstlane(src_perm[i + 2]);
    int s3 = __builtin_amdgcn_readfirstlane(src_perm[i + 3]);
    unsigned int hv0 = h2[(size_t)s0 * 64 + lane];
    unsigned int hv1 = h2[(size_t)s1 * 64 + lane];
    unsigned int hv2 = h2[(size_t)s2 * 64 + lane];
    unsigned int hv3 = h2[(size_t)s3 * 64 + lane];
    unsigned int ev0 = encp[(size_t)i * 64 + lane];
    unsigned int ev1 = encp[(size_t)(i + 1) * 64 + lane];
    unsigned int ev2 = encp[(size_t)(i + 2) * 64 + lane];
    unsigned int ev3 = encp[(size_t)(i + 3) * 64 + lane];
    ax += fmaxf(bf_lo(ev0) + bf_lo(hv0), 0.f) +
          fmaxf(bf_lo(ev1) + bf_lo(hv1), 0.f) +
          fmaxf(bf_lo(ev2) + bf_lo(hv2), 0.f) +
          fmaxf(bf_lo(ev3) + bf_lo(hv3), 0.f);
    ay += fmaxf(bf_hi(ev0) + bf_hi(hv0), 0.f) +
          fmaxf(bf_hi(ev1) + bf_hi(hv1), 0.f) +
          fmaxf(bf_hi(ev2) + bf_hi(hv2), 0.f) +
          fmaxf(bf_hi(ev3) + bf_hi(hv3), 0.f);
  }
  for (; i < end; ++i) {
    int s0 = __builtin_amdgcn_readfirstlane(src_perm[i]);
    unsigned int hv0 = h2[(size_t)s0 * 64 + lane];
    unsigned int ev0 = encp[(size_t)i * 64 + lane];
    ax += fmaxf(bf_lo(ev0) + bf_lo(hv0), 0.f);
    ay += fmaxf(bf_hi(ev0) + bf_hi(hv0), 0.f);
  }
  unsigned int hn = h2[(size_t)n * 64 + lane];
  *(float2*)&z[(size_t)n * H + lane * 2] =
      make_float2(bf_lo(hn) + ax, bf_hi(hn) + ay);
}

// ---- aggregation (fallback, small ws): recompute enc from fp32 ea ---------
__global__ __launch_bounds__(256) void aggr_fb(const float* __restrict__ ea,
    const float* __restrict__ ew, const float* __restrict__ eb,
    const int* __restrict__ perm, const int* __restrict__ src_perm,
    const int* __restrict__ off, const unsigned int* __restrict__ h2,
    float* __restrict__ z, int N) {
  int wid = threadIdx.x >> 6, lane = threadIdx.x & 63;
  int n = blockIdx.x * 4 + wid;
  if (n >= N) return;
  int beg = off[n], end = off[n + 1];
  int c = lane * 2;
  float2 wc[16];
#pragma unroll
  for (int k = 0; k < 16; ++k) wc[k] = *(const float2*)&ew[k * H + c];
  float2 bias = *(const float2*)&eb[c];
  float ax = 0.f, ay = 0.f;
  int i = beg;
  for (; i + 2 <= end; i += 2) {
    int e0 = __builtin_amdgcn_readfirstlane(perm[i]);
    int e1 = __builtin_amdgcn_readfirstlane(perm[i + 1]);
    int s0 = __builtin_amdgcn_readfirstlane(src_perm[i]);
    int s1 = __builtin_amdgcn_readfirstlane(src_perm[i + 1]);
    unsigned int hv0 = h2[(size_t)s0 * 64 + lane];
    unsigned int hv1 = h2[(size_t)s1 * 64 + lane];
    const float* a0 = ea + (size_t)e0 * 16;
    const float* a1 = ea + (size_t)e1 * 16;
    float x0 = bias.x, y0 = bias.y, x1 = bias.x, y1 = bias.y;
#pragma unroll
    for (int k = 0; k < 16; ++k) {
      float a0k = a0[k], a1k = a1[k];
      x0 = fmaf(a0k, wc[k].x, x0);
      y0 = fmaf(a0k, wc[k].y, y0);
      x1 = fmaf(a1k, wc[k].x, x1);
      y1 = fmaf(a1k, wc[k].y, y1);
    }
    ax += fmaxf(x0 + bf_lo(hv0), 0.f) + fmaxf(x1 + bf_lo(hv1), 0.f);
    ay += fmaxf(y0 + bf_hi(hv0), 0.f) + fmaxf(y1 + bf_hi(hv1), 0.f);
  }
  if (i < end) {
    int e0 = __builtin_amdgcn_readfirstlane(perm[i]);
    int s0 = __builtin_amdgcn_readfirstlane(src_perm[i]);
    unsigned int hv0 = h2[(size_t)s0 * 64 + lane];
    const float* a0 = ea + (size_t)e0 * 16;
    float x0 = bias.x, y0 = bias.y;
#pragma unroll
    for (int k = 0; k < 16; ++k) {
      float a0k = a0[k];
      x0 = fmaf(a0k, wc[k].x, x0);
      y0 = fmaf(a0k, wc[k].y, y0);
    }
    ax += fmaxf(x0 + bf_lo(hv0), 0.f);
    ay += fmaxf(y0 + bf_hi(hv0), 0.f);
  }
  unsigned int hn = h2[(size_t)n * 64 + lane];
  *(float2*)&z[(size_t)n * H + c] = make_float2(bf_lo(hn) + ax, bf_hi(hn) + ay);
}

// ---- GEMM1: t = z @ w1 + b1, 64x128 tile, 8r x 4c per thread --------------
__global__ __launch_bounds__(256) void mlp1(const float* __restrict__ zin,
    const float* __restrict__ w1, const float* __restrict__ b1,
    float* __restrict__ tout, float* __restrict__ sum,
    float* __restrict__ sumsq, int N) {
  int r0 = blockIdx.x * TM;
  int tid = threadIdx.x;
  int cl = tid & 31;
  int rg = tid >> 5;
  int c0 = cl * 4;
  __shared__ float z[TM][H];
  const float4* zin4 = (const float4*)zin;
#pragma unroll
  for (int f = 0; f < 8; ++f) {
    int q = f * 256 + tid;
    int row = q >> 5, col4 = q & 31;
    int g = r0 + row;
    float4 v = make_float4(0.f, 0.f, 0.f, 0.f);
    if (g < N) v = zin4[(size_t)g * 32 + col4];
    *(float4*)&z[row][col4 * 4] = v;
  }
  __syncthreads();
  float4 bv = *(const float4*)&b1[c0];
  float acc[8][4];
#pragma unroll
  for (int r = 0; r < 8; ++r) {
    acc[r][0] = bv.x; acc[r][1] = bv.y; acc[r][2] = bv.z; acc[r][3] = bv.w;
  }
  int zr = rg * 8;
#pragma unroll 4
  for (int k4 = 0; k4 < 32; ++k4) {
    float4 wa = *(const float4*)&w1[(k4 * 4 + 0) * H + c0];
    float4 wb = *(const float4*)&w1[(k4 * 4 + 1) * H + c0];
    float4 wc = *(const float4*)&w1[(k4 * 4 + 2) * H + c0];
    float4 wd = *(const float4*)&w1[(k4 * 4 + 3) * H + c0];
#pragma unroll
    for (int r = 0; r < 8; ++r) {
      float4 zv = *(const float4*)&z[zr + r][k4 * 4];
      acc[r][0] = fmaf(zv.x, wa.x, acc[r][0]);
      acc[r][1] = fmaf(zv.x, wa.y, acc[r][1]);
      acc[r][2] = fmaf(zv.x, wa.z, acc[r][2]);
      acc[r][3] = fmaf(zv.x, wa.w, acc[r][3]);
      acc[r][0] = fmaf(zv.y, wb.x, acc[r][0]);
      acc[r][1] = fmaf(zv.y, wb.y, acc[r][1]);
      acc[r][2] = fmaf(zv.y, wb.z, acc[r][2]);
      acc[r][3] = fmaf(zv.y, wb.w, acc[r][3]);
      acc[r][0] = fmaf(zv.z, wc.x, acc[r][0]);
      acc[r][1] = fmaf(zv.z, wc.y, acc[r][1]);
      acc[r][2] = fmaf(zv.z, wc.z, acc[r][2]);
      acc[r][3] = fmaf(zv.z, wc.w, acc[r][3]);
      acc[r][0] = fmaf(zv.w, wd.x, acc[r][0]);
      acc[r][1] = fmaf(zv.w, wd.y, acc[r][1]);
      acc[r][2] = fmaf(zv.w, wd.z, acc[r][2]);
      acc[r][3] = fmaf(zv.w, wd.w, acc[r][3]);
    }
  }
  float s1[4] = {0.f, 0.f, 0.f, 0.f}, s2[4] = {0.f, 0.f, 0.f, 0.f};
#pragma unroll
  for (int r = 0; r < 8; ++r) {
    int g = r0 + zr + r;
    if (g < N) {
      *(float4*)&tout[(size_t)g * H + c0] =
          make_float4(acc[r][0], acc[r][1], acc[r][2], acc[r][3]);
#pragma unroll
      for (int c = 0; c < 4; ++c) {
        s1[c] += acc[r][c];
        s2[c] += acc[r][c] * acc[r][c];
      }
    }
  }
  __syncthreads();
  float* red = &z[0][0];
#pragma unroll
  for (int c = 0; c < 4; ++c) {
    red[rg * H + c0 + c] = s1[c];
    red[1024 + rg * H + c0 + c] = s2[c];
  }
  __syncthreads();
  if (tid < H) {
    float a = 0.f, b = 0.f;
#pragma unroll
    for (int g = 0; g < 8; ++g) {
      a += red[g * H + tid];
      b += red[1024 + g * H + tid];
    }
    atomicAdd(&sum[tid], a);
    atomicAdd(&sumsq[tid], b);
  }
}

// ---- BN finalize ----------------------------------------------------------
__global__ void bn_finalize(const float* __restrict__ sum,
    const float* __restrict__ sumsq, const float* __restrict__ g,
    const float* __restrict__ beta, float* __restrict__ scale,
    float* __restrict__ shift, float invN) {
  int j = threadIdx.x;
  float mu = sum[j] * invN;
  float var = sumsq[j] * invN - mu * mu;
  float inv = rsqrtf(var + 1e-5f);
  float sc = g[j] * inv;
  scale[j] = sc;
  shift[j] = beta[j] - mu * sc;
}

// ---- GEMM2: h2 = bf16(relu( relu(t*sc+sh) @ w2 + b2 )), fused pool last ---
__global__ __launch_bounds__(256) void mlp2(const float* __restrict__ tin,
    const float* __restrict__ scale, const float* __restrict__ shift,
    const float* __restrict__ w2, const float* __restrict__ b2,
    unsigned int* __restrict__ h2out, int N,
    const int* __restrict__ batch, float* __restrict__ pooled) {
  int r0 = blockIdx.x * TM;
  int tid = threadIdx.x;
  int cl = tid & 31;
  int rg = tid >> 5;
  int c0 = cl * 4;
  __shared__ float z[TM][H];
  const float4* tin4 = (const float4*)tin;
#pragma unroll
  for (int f = 0; f < 8; ++f) {
    int q = f * 256 + tid;
    int row = q >> 5, col4 = q & 31;
    int g = r0 + row;
    float4 v = make_float4(0.f, 0.f, 0.f, 0.f);
    if (g < N) {
      v = tin4[(size_t)g * 32 + col4];
      float4 sc = *(const float4*)&scale[col4 * 4];
      float4 sh = *(const float4*)&shift[col4 * 4];
      v.x = fmaxf(fmaf(v.x, sc.x, sh.x), 0.f);
      v.y = fmaxf(fmaf(v.y, sc.y, sh.y), 0.f);
      v.z = fmaxf(fmaf(v.z, sc.z, sh.z), 0.f);
      v.w = fmaxf(fmaf(v.w, sc.w, sh.w), 0.f);
    }
    *(float4*)&z[row][col4 * 4] = v;
  }
  __syncthreads();
  float4 bv = *(const float4*)&b2[c0];
  float acc[8][4];
#pragma unroll
  for (int r = 0; r < 8; ++r) {
    acc[r][0] = bv.x; acc[r][1] = bv.y; acc[r][2] = bv.z; acc[r][3] = bv.w;
  }
  int zr = rg * 8;
#pragma unroll 4
  for (int k4 = 0; k4 < 32; ++k4) {
    float4 wa = *(const float4*)&w2[(k4 * 4 + 0) * H + c0];
    float4 wb = *(const float4*)&w2[(k4 * 4 + 1) * H + c0];
    float4 wc = *(const float4*)&w2[(k4 * 4 + 2) * H + c0];
    float4 wd = *(const float4*)&w2[(k4 * 4 + 3) * H + c0];
#pragma unroll
    for (int r = 0; r < 8; ++r) {
      float4 zv = *(const float4*)&z[zr + r][k4 * 4];
      acc[r][0] = fmaf(zv.x, wa.x, acc[r][0]);
      acc[r][1] = fmaf(zv.x, wa.y, acc[r][1]);
      acc[r][2] = fmaf(zv.x, wa.z, acc[r][2]);
      acc[r][3] = fmaf(zv.x, wa.w, acc[r][3]);
      acc[r][0] = fmaf(zv.y, wb.x, acc[r][0]);
      acc[r][1] = fmaf(zv.y, wb.y, acc[r][1]);
      acc[r][2] = fmaf(zv.y, wb.z, acc[r][2]);
      acc[r][3] = fmaf(zv.y, wb.w, acc[r][3]);
      acc[r][0] = fmaf(zv.z, wc.x, acc[r][0]);
      acc[r][1] = fmaf(zv.z, wc.y, acc[r][1]);
      acc[r][2] = fmaf(zv.z, wc.z, acc[r][2]);
      acc[r][3] = fmaf(zv.z, wc.w, acc[r][3]);
      acc[r][0] = fmaf(zv.w, wd.x, acc[r][0]);
      acc[r][1] = fmaf(zv.w, wd.y, acc[r][1]);
      acc[r][2] = fmaf(zv.w, wd.z, acc[r][2]);
      acc[r][3] = fmaf(zv.w, wd.w, acc[r][3]);
    }
  }
#pragma unroll
  for (int r = 0; r < 8; ++r) {
#pragma unroll
    for (int c = 0; c < 4; ++c) acc[r][c] = fmaxf(acc[r][c], 0.f);
  }
  if (h2out != nullptr) {
#pragma unroll
    for (int r = 0; r < 8; ++r) {
      int g = r0 + zr + r;
      if (g < N) {
        unsigned int d0 = bfr(acc[r][0]) | (bfr(acc[r][1]) << 16);
        unsigned int d1 = bfr(acc[r][2]) | (bfr(acc[r][3]) << 16);
        *(uint2*)&h2out[(size_t)g * 64 + (c0 >> 1)] = make_uint2(d0, d1);
      }
    }
  }
  if (pooled != nullptr) {
    int gbase = r0 + zr;
    if (gbase < N) {
      int cur = batch[gbase];
      float pa[4] = {0.f, 0.f, 0.f, 0.f};
      for (int r = 0; r < 8; ++r) {
        int g = gbase + r;
        if (g >= N) break;
        int bb = batch[g];
        if (bb != cur) {
#pragma unroll
          for (int c = 0; c < 4; ++c)
            atomicAdd(&pooled[(size_t)cur * H + c0 + c], pa[c]);
          pa[0] = pa[1] = pa[2] = pa[3] = 0.f;
          cur = bb;
        }
#pragma unroll
        for (int c = 0; c < 4; ++c) pa[c] += acc[r][c];
      }
#pragma unroll
      for (int c = 0; c < 4; ++c)
        atomicAdd(&pooled[(size_t)cur * H + c0 + c], pa[c]);
    }
  }
}

// ---- final FC: out = pooled @ fc_w + fc_b ---------------------------------
__global__ __launch_bounds__(128) void fc_kernel(const float* __restrict__ pooled,
    const float* __restrict__ w, const float* __restrict__ b,
    float* __restrict__ out, int C) {
  int g = blockIdx.x;
  int j = threadIdx.x;
  __shared__ float p[H];
  p[j] = pooled[(size_t)g * H + j];
  __syncthreads();
  if (j < C) {
    float acc = b[j];
#pragma unroll 4
    for (int k = 0; k < H; ++k) acc = fmaf(p[k], w[k * C + j], acc);
    out[(size_t)g * C + j] = acc;
  }
}

extern "C" void kernel_launch(void* const* d_in, const int* in_sizes, int n_in,
                              void* d_out, int out_size, void* d_ws, size_t ws_size,
                              hipStream_t stream) {
  const float* x         = (const float*)d_in[0];
  const float* edge_attr = (const float*)d_in[1];
  const float* node_w    = (const float*)d_in[2];
  const float* node_b    = (const float*)d_in[3];
  const float* edge_w    = (const float*)d_in[4];
  const float* edge_b    = (const float*)d_in[5];
  const float* lin1_w    = (const float*)d_in[6];
  const float* lin1_b    = (const float*)d_in[7];
  const float* bn_g      = (const float*)d_in[8];
  const float* bn_b      = (const float*)d_in[9];
  const float* lin2_w    = (const float*)d_in[10];
  const float* lin2_b    = (const float*)d_in[11];
  const float* fc_w      = (const float*)d_in[12];
  const float* fc_b      = (const float*)d_in[13];
  const int*   edge_index= (const int*)d_in[14];
  const int*   batch     = (const int*)d_in[15];

  int N = in_sizes[0] / 64;       // 50000
  int E = in_sizes[1] / 16;       // 640000
  int C = in_sizes[13];           // 10
  int G = out_size / C;           // 512

  const int* src = edge_index;
  const int* dst = edge_index + E;

  float* ws     = (float*)d_ws;
  float* zt     = ws;                        // [N,H]
  float* pooled = zt + (size_t)N * H;        // [G,H]
  float* sums   = pooled + (size_t)G * H;
  float* sumsq  = sums + H;
  float* scale  = sumsq + H;
  float* shift  = scale + H;
  unsigned int* h2 = (unsigned int*)(shift + H);  // [N,64] packed bf16
  int*   cnt      = (int*)(h2 + (size_t)N * 64);
  int*   off      = cnt + N;
  int*   cursor   = off + N + 1;
  int*   src_perm = cursor + N;              // [E]
  int*   perm     = src_perm + E;            // [E]
  int*   bsum     = perm + E;                // [1024]
  int*   bbase    = bsum + 1024;             // [1024]
  unsigned int* encp = (unsigned int*)(bbase + 1024);  // [E,64] packed bf16

  size_t needed = ((char*)(encp + (size_t)E * 64)) - (char*)d_ws;
  bool useEnc = (ws_size >= needed);

  int nb = (N + 255) / 256;

  // --- CSR build (every launch; deterministic) ---
  hipMemsetAsync(cnt, 0, (size_t)N * sizeof(int), stream);
  count_deg<<<(E + 255) / 256, 256, 0, stream>>>(dst, cnt, E);
  block_sum<<<nb, 256, 0, stream>>>(cnt, bsum, N);
  scan_bsum<<<1, 1024, 0, stream>>>(bsum, bbase, nb);
  scan_pass<<<nb, 256, 0, stream>>>(cnt, bbase, off, cursor, N);
  scatter_csr<<<(E + 255) / 256, 256, 0, stream>>>(src, dst, cursor, perm, src_perm, E);

  node_enc<<<N, 128, 0, stream>>>(x, node_w, node_b, h2, N);

  if (useEnc) {
    const int eblk = 2048;                   // 8192 waves
    int chunk = (E + eblk * 4 - 1) / (eblk * 4);
    enc_edges<<<eblk, 256, 0, stream>>>(edge_attr, edge_w, edge_b, perm,
                                        encp, E, chunk);
  }

  int mblk = (N + TM - 1) / TM;
  int ablk = (N + 3) / 4;
  for (int l = 0; l < 3; ++l) {
    hipMemsetAsync(sums, 0, 2 * H * sizeof(float), stream);
    if (useEnc) {
      aggr_enc<<<ablk, 256, 0, stream>>>(encp, src_perm, off, h2, zt, N);
    } else {
      aggr_fb<<<ablk, 256, 0, stream>>>(edge_attr, edge_w, edge_b, perm,
                                        src_perm, off, h2, zt, N);
    }
    mlp1<<<mblk, 256, 0, stream>>>(zt, lin1_w + (size_t)l * H * H,
                                   lin1_b + (size_t)l * H, zt, sums, sumsq, N);
    bn_finalize<<<1, H, 0, stream>>>(sums, sumsq, bn_g + (size_t)l * H,
                                     bn_b + (size_t)l * H, scale, shift, 1.0f / N);
    bool last = (l == 2);
    if (last) hipMemsetAsync(pooled, 0, (size_t)G * H * sizeof(float), stream);
    mlp2<<<mblk, 256, 0, stream>>>(zt, scale, shift, lin2_w + (size_t)l * H * H,
                                   lin2_b + (size_t)l * H,
                                   last ? nullptr : h2, N,
                                   batch, last ? pooled : nullptr);
  }

  fc_kernel<<<G, 128, 0, stream>>>(pooled, fc_w, fc_b, (float*)d_out, C);
}

// Round 9
// 629.771 us; speedup vs baseline: 1.4132x; 1.3581x over previous
//
#include <hip/hip_runtime.h>

#define H   128

typedef __attribute__((ext_vector_type(8))) short short8;
typedef __attribute__((ext_vector_type(4))) float f32x4;

// bf16 round-to-nearest-even of fp32, returns low 16 bits
__device__ __forceinline__ unsigned int bfr(float f) {
  unsigned int u = __float_as_uint(f);
  return (u + 0x7fffu + ((u >> 16) & 1u)) >> 16;
}
__device__ __forceinline__ float bf_lo(unsigned int d) {
  return __uint_as_float(d << 16);
}
__device__ __forceinline__ float bf_hi(unsigned int d) {
  return __uint_as_float(d & 0xffff0000u);
}

// ---------------- node encoder: h2 = bf16(x @ node_w + node_b) -------------
__global__ __launch_bounds__(128) void node_enc(const float* __restrict__ x,
    const float* __restrict__ w, const float* __restrict__ b,
    unsigned int* __restrict__ h2, int N) {
  int row = blockIdx.x;
  if (row >= N) return;
  int j = threadIdx.x;
  __shared__ float xs[64];
  if (j < 64) xs[j] = x[(size_t)row * 64 + j];
  __syncthreads();
  float acc = b[j];
#pragma unroll
  for (int k = 0; k < 64; ++k) acc = fmaf(xs[k], w[k * H + j], acc);
  float part = __shfl_down(acc, 1, 64);
  if ((j & 1) == 0) {
    unsigned int d = bfr(acc) | (bfr(part) << 16);
    h2[(size_t)row * 64 + (j >> 1)] = d;
  }
}

// ---------------- CSR build: degree count ----------------------------------
__global__ __launch_bounds__(256) void count_deg(const int* __restrict__ dst,
    int* __restrict__ cnt, int E) {
  int e = blockIdx.x * 256 + threadIdx.x;
  if (e < E) atomicAdd(&cnt[dst[e]], 1);
}

// ---------------- scan pass 1 ----------------------------------------------
__global__ __launch_bounds__(256) void block_sum(const int* __restrict__ cnt,
    int* __restrict__ bsum, int N) {
  int t = threadIdx.x;
  int i = blockIdx.x * 256 + t;
  int v = (i < N) ? cnt[i] : 0;
#pragma unroll
  for (int o = 32; o > 0; o >>= 1) v += __shfl_down(v, o, 64);
  __shared__ int wt[4];
  if ((t & 63) == 0) wt[t >> 6] = v;
  __syncthreads();
  if (t == 0) bsum[blockIdx.x] = wt[0] + wt[1] + wt[2] + wt[3];
}

// ---------------- scan pass 2 ----------------------------------------------
__global__ __launch_bounds__(1024) void scan_bsum(const int* __restrict__ bsum,
    int* __restrict__ bbase, int nb) {
  __shared__ int s[1024];
  int t = threadIdx.x;
  int v = (t < nb) ? bsum[t] : 0;
  s[t] = v;
  __syncthreads();
  for (int o = 1; o < 1024; o <<= 1) {
    int u = (t >= o) ? s[t - o] : 0;
    __syncthreads();
    s[t] += u;
    __syncthreads();
  }
  if (t < nb) bbase[t] = s[t] - v;
}

// ---------------- scan pass 3 ----------------------------------------------
__global__ __launch_bounds__(256) void scan_pass(const int* __restrict__ cnt,
    const int* __restrict__ bbase, int* __restrict__ off,
    int* __restrict__ cursor, int N) {
  int t = threadIdx.x;
  int i = blockIdx.x * 256 + t;
  int v = (i < N) ? cnt[i] : 0;
  int lane = t & 63;
  int incl = v;
#pragma unroll
  for (int o = 1; o < 64; o <<= 1) {
    int u = __shfl_up(incl, o, 64);
    if (lane >= o) incl += u;
  }
  __shared__ int wtot[4];
  int w = t >> 6;
  if (lane == 63) wtot[w] = incl;
  __syncthreads();
  if (t == 0) {
    int run = 0;
#pragma unroll
    for (int k = 0; k < 4; ++k) { int tmp = wtot[k]; wtot[k] = run; run += tmp; }
  }
  __syncthreads();
  int excl = incl - v + wtot[w] + bbase[blockIdx.x];
  if (i < N) { off[i] = excl; cursor[i] = excl; }
  if (i == N - 1) off[N] = excl + v;
}

// ---------------- CSR build: scatter ---------------------------------------
__global__ __launch_bounds__(256) void scatter_csr(const int* __restrict__ src,
    const int* __restrict__ dst, int* __restrict__ cursor,
    int* __restrict__ perm, int* __restrict__ src_perm, int E) {
  int e = blockIdx.x * 256 + threadIdx.x;
  if (e < E) {
    int pos = atomicAdd(&cursor[dst[e]], 1);
    perm[pos] = e;
    src_perm[pos] = src[e];
  }
}

// ---------------- weight pack: fp32 [128][128] -> bf16 MFMA-B fragments ----
// wp[mat][kt][ct][lane][j] = bf16( w[kt*32 + (lane>>4)*8 + j][ct*16 + (lane&15)] )
__global__ __launch_bounds__(256) void wpack(const float* __restrict__ w1,
    const float* __restrict__ w2, unsigned short* __restrict__ wp, int L) {
  int idx = blockIdx.x * 256 + threadIdx.x;
  int total = L * 2 * 16384;
  if (idx >= total) return;
  int j    = idx & 7;
  int lane = (idx >> 3) & 63;
  int ct   = (idx >> 9) & 7;
  int kt   = (idx >> 12) & 3;
  int mat  = idx >> 14;
  int l = mat >> 1, which = mat & 1;
  const float* w = (which == 0 ? w1 : w2) + (size_t)l * H * H;
  int k = kt * 32 + (lane >> 4) * 8 + j;
  int n = ct * 16 + (lane & 15);
  wp[idx] = (unsigned short)bfr(w[k * H + n]);
}

// ---- CSR aggregation: zb[n] = bf16( h[n] + sum relu(h[src]+ea[e]@ew+eb) ) -
// Wave-per-node (R6 structure). fp32 ea via wave-uniform s_loads, bf16 h
// gathers, packed-bf16 z output.
__global__ __launch_bounds__(256) void aggr_csr(const float* __restrict__ ea,
    const float* __restrict__ ew, const float* __restrict__ eb,
    const int* __restrict__ perm, const int* __restrict__ src_perm,
    const int* __restrict__ off, const unsigned int* __restrict__ h2,
    unsigned int* __restrict__ zb, int N) {
  int wid = threadIdx.x >> 6, lane = threadIdx.x & 63;
  int n = blockIdx.x * 4 + wid;
  if (n >= N) return;
  int beg = off[n], end = off[n + 1];
  int c = lane * 2;
  float2 wc[16];
#pragma unroll
  for (int k = 0; k < 16; ++k) wc[k] = *(const float2*)&ew[k * H + c];
  float2 bias = *(const float2*)&eb[c];
  float ax = 0.f, ay = 0.f;
  int i = beg;
  for (; i + 2 <= end; i += 2) {
    int e0 = __builtin_amdgcn_readfirstlane(perm[i]);
    int e1 = __builtin_amdgcn_readfirstlane(perm[i + 1]);
    int s0 = __builtin_amdgcn_readfirstlane(src_perm[i]);
    int s1 = __builtin_amdgcn_readfirstlane(src_perm[i + 1]);
    unsigned int hv0 = h2[(size_t)s0 * 64 + lane];
    unsigned int hv1 = h2[(size_t)s1 * 64 + lane];
    const float* a0 = ea + (size_t)e0 * 16;
    const float* a1 = ea + (size_t)e1 * 16;
    float x0 = bias.x, y0 = bias.y, x1 = bias.x, y1 = bias.y;
#pragma unroll
    for (int k = 0; k < 16; ++k) {
      float a0k = a0[k], a1k = a1[k];
      x0 = fmaf(a0k, wc[k].x, x0);
      y0 = fmaf(a0k, wc[k].y, y0);
      x1 = fmaf(a1k, wc[k].x, x1);
      y1 = fmaf(a1k, wc[k].y, y1);
    }
    ax += fmaxf(x0 + bf_lo(hv0), 0.f) + fmaxf(x1 + bf_lo(hv1), 0.f);
    ay += fmaxf(y0 + bf_hi(hv0), 0.f) + fmaxf(y1 + bf_hi(hv1), 0.f);
  }
  if (i < end) {
    int e0 = __builtin_amdgcn_readfirstlane(perm[i]);
    int s0 = __builtin_amdgcn_readfirstlane(src_perm[i]);
    unsigned int hv0 = h2[(size_t)s0 * 64 + lane];
    const float* a0 = ea + (size_t)e0 * 16;
    float x0 = bias.x, y0 = bias.y;
#pragma unroll
    for (int k = 0; k < 16; ++k) {
      float a0k = a0[k];
      x0 = fmaf(a0k, wc[k].x, x0);
      y0 = fmaf(a0k, wc[k].y, y0);
    }
    ax += fmaxf(x0 + bf_lo(hv0), 0.f);
    ay += fmaxf(y0 + bf_hi(hv0), 0.f);
  }
  unsigned int hn = h2[(size_t)n * 64 + lane];
  float zx = bf_lo(hn) + ax, zy = bf_hi(hn) + ay;
  zb[(size_t)n * 64 + lane] = bfr(zx) | (bfr(zy) << 16);
}

// ---- MFMA GEMM1: t = zb @ w1 + b1 (fp32 out) + BN column sums -------------
// Block 256 = 4 waves, 64 rows; wave = 16 rows x 128 cols via 8 col-tiles.
__global__ __launch_bounds__(256) void mlp1m(const unsigned short* __restrict__ zb,
    const unsigned short* __restrict__ wp, const float* __restrict__ b1,
    float* __restrict__ tout, float* __restrict__ sum,
    float* __restrict__ sumsq, int N) {
  int tid = threadIdx.x;
  int wave = tid >> 6, lane = tid & 63;
  int q = lane >> 4, m = lane & 15;
  int r0 = blockIdx.x * 64 + wave * 16;
  f32x4 acc[8];
#pragma unroll
  for (int ct = 0; ct < 8; ++ct) acc[ct] = (f32x4){0.f, 0.f, 0.f, 0.f};
#pragma unroll
  for (int kt = 0; kt < 4; ++kt) {
    short8 a = *(const short8*)(zb + (size_t)(r0 + m) * H + kt * 32 + q * 8);
#pragma unroll
    for (int ct = 0; ct < 8; ++ct) {
      short8 b = *(const short8*)(wp + ((size_t)(kt * 8 + ct) * 64 + lane) * 8);
      acc[ct] = __builtin_amdgcn_mfma_f32_16x16x32_bf16(a, b, acc[ct], 0, 0, 0);
    }
  }
  __shared__ float red[2][H][16];
  int wq = wave * 4 + q;
#pragma unroll
  for (int ct = 0; ct < 8; ++ct) {
    int col = ct * 16 + m;
    float bias = b1[col];
    float s1 = 0.f, s2 = 0.f;
#pragma unroll
    for (int r = 0; r < 4; ++r) {
      int gr = r0 + q * 4 + r;
      float v = acc[ct][r] + bias;
      if (gr < N) {
        tout[(size_t)gr * H + col] = v;
        s1 += v;
        s2 += v * v;
      }
    }
    red[0][col][wq] = s1;
    red[1][col][wq] = s2;
  }
  __syncthreads();
  if (tid < H) {
    float a = 0.f, b = 0.f;
#pragma unroll
    for (int g = 0; g < 16; ++g) {
      a += red[0][tid][g];
      b += red[1][tid][g];
    }
    atomicAdd(&sum[tid], a);
    atomicAdd(&sumsq[tid], b);
  }
}

// ---- BN finalize ----------------------------------------------------------
__global__ void bn_finalize(const float* __restrict__ sum,
    const float* __restrict__ sumsq, const float* __restrict__ g,
    const float* __restrict__ beta, float* __restrict__ scale,
    float* __restrict__ shift, float invN) {
  int j = threadIdx.x;
  float mu = sum[j] * invN;
  float var = sumsq[j] * invN - mu * mu;
  float inv = rsqrtf(var + 1e-5f);
  float sc = g[j] * inv;
  scale[j] = sc;
  shift[j] = beta[j] - mu * sc;
}

// ---- MFMA GEMM2: h = relu( relu(t*sc+sh) @ w2 + b2 ); bf16 out or pool ----
__global__ __launch_bounds__(256) void mlp2m(const float* __restrict__ tin,
    const float* __restrict__ scale, const float* __restrict__ shift,
    const unsigned short* __restrict__ wp, const float* __restrict__ b2,
    unsigned short* __restrict__ hout, int N,
    const int* __restrict__ batch, float* __restrict__ pooled) {
  int tid = threadIdx.x;
  int wave = tid >> 6, lane = tid & 63;
  int q = lane >> 4, m = lane & 15;
  int r0 = blockIdx.x * 64 + wave * 16;
  f32x4 acc[8];
#pragma unroll
  for (int ct = 0; ct < 8; ++ct) acc[ct] = (f32x4){0.f, 0.f, 0.f, 0.f};
#pragma unroll
  for (int kt = 0; kt < 4; ++kt) {
    int col0 = kt * 32 + q * 8;
    f32x4 t0 = *(const f32x4*)(tin + (size_t)(r0 + m) * H + col0);
    f32x4 t1 = *(const f32x4*)(tin + (size_t)(r0 + m) * H + col0 + 4);
    f32x4 sc0 = *(const f32x4*)(scale + col0);
    f32x4 sc1 = *(const f32x4*)(scale + col0 + 4);
    f32x4 sh0 = *(const f32x4*)(shift + col0);
    f32x4 sh1 = *(const f32x4*)(shift + col0 + 4);
    short8 a;
#pragma unroll
    for (int j = 0; j < 4; ++j) {
      float v = fmaxf(fmaf(t0[j], sc0[j], sh0[j]), 0.f);
      a[j] = (short)bfr(v);
    }
#pragma unroll
    for (int j = 0; j < 4; ++j) {
      float v = fmaxf(fmaf(t1[j], sc1[j], sh1[j]), 0.f);
      a[4 + j] = (short)bfr(v);
    }
#pragma unroll
    for (int ct = 0; ct < 8; ++ct) {
      short8 b = *(const short8*)(wp + ((size_t)(kt * 8 + ct) * 64 + lane) * 8);
      acc[ct] = __builtin_amdgcn_mfma_f32_16x16x32_bf16(a, b, acc[ct], 0, 0, 0);
    }
  }
  // epilogue: bias + relu
#pragma unroll
  for (int ct = 0; ct < 8; ++ct) {
    float bias = b2[ct * 16 + m];
#pragma unroll
    for (int r = 0; r < 4; ++r) acc[ct][r] = fmaxf(acc[ct][r] + bias, 0.f);
  }
  if (hout != nullptr) {
#pragma unroll
    for (int r = 0; r < 4; ++r) {
      int gr = r0 + q * 4 + r;
      if (gr < N) {
#pragma unroll
        for (int ct = 0; ct < 8; ++ct)
          hout[(size_t)gr * H + ct * 16 + m] = (unsigned short)bfr(acc[ct][r]);
      }
    }
  }
  if (pooled != nullptr) {
    int bprev = -1;
    float pa[8];
#pragma unroll
    for (int ct = 0; ct < 8; ++ct) pa[ct] = 0.f;
    for (int r = 0; r < 4; ++r) {
      int gr = r0 + q * 4 + r;
      if (gr >= N) break;
      int bb = batch[gr];
      if (bb != bprev && bprev >= 0) {
#pragma unroll
        for (int ct = 0; ct < 8; ++ct) {
          atomicAdd(&pooled[(size_t)bprev * H + ct * 16 + m], pa[ct]);
          pa[ct] = 0.f;
        }
      }
      bprev = bb;
#pragma unroll
      for (int ct = 0; ct < 8; ++ct) pa[ct] += acc[ct][r];
    }
    if (bprev >= 0) {
#pragma unroll
      for (int ct = 0; ct < 8; ++ct)
        atomicAdd(&pooled[(size_t)bprev * H + ct * 16 + m], pa[ct]);
    }
  }
}

// ---- final FC: out = pooled @ fc_w + fc_b ---------------------------------
__global__ __launch_bounds__(128) void fc_kernel(const float* __restrict__ pooled,
    const float* __restrict__ w, const float* __restrict__ b,
    float* __restrict__ out, int C) {
  int g = blockIdx.x;
  int j = threadIdx.x;
  __shared__ float p[H];
  p[j] = pooled[(size_t)g * H + j];
  __syncthreads();
  if (j < C) {
    float acc = b[j];
#pragma unroll 4
    for (int k = 0; k < H; ++k) acc = fmaf(p[k], w[k * C + j], acc);
    out[(size_t)g * C + j] = acc;
  }
}

extern "C" void kernel_launch(void* const* d_in, const int* in_sizes, int n_in,
                              void* d_out, int out_size, void* d_ws, size_t ws_size,
                              hipStream_t stream) {
  const float* x         = (const float*)d_in[0];
  const float* edge_attr = (const float*)d_in[1];
  const float* node_w    = (const float*)d_in[2];
  const float* node_b    = (const float*)d_in[3];
  const float* edge_w    = (const float*)d_in[4];
  const float* edge_b    = (const float*)d_in[5];
  const float* lin1_w    = (const float*)d_in[6];
  const float* lin1_b    = (const float*)d_in[7];
  const float* bn_g      = (const float*)d_in[8];
  const float* bn_b      = (const float*)d_in[9];
  const float* lin2_w    = (const float*)d_in[10];
  const float* lin2_b    = (const float*)d_in[11];
  const float* fc_w      = (const float*)d_in[12];
  const float* fc_b      = (const float*)d_in[13];
  const int*   edge_index= (const int*)d_in[14];
  const int*   batch     = (const int*)d_in[15];

  int N = in_sizes[0] / 64;       // 50000
  int E = in_sizes[1] / 16;       // 640000
  int C = in_sizes[13];           // 10
  int G = out_size / C;           // 512

  const int* src = edge_index;
  const int* dst = edge_index + E;

  int mblk = (N + 63) / 64;
  int Npad = mblk * 64;           // 50048

  float* t      = (float*)d_ws;              // [Npad,H] fp32
  float* pooled = t + (size_t)Npad * H;      // [G,H]
  float* sums   = pooled + (size_t)G * H;
  float* sumsq  = sums + H;
  float* scale  = sumsq + H;
  float* shift  = scale + H;
  unsigned int* h2 = (unsigned int*)(shift + H);     // [Npad,64] packed bf16
  unsigned int* zb = h2 + (size_t)Npad * 64;         // [Npad,64] packed bf16
  unsigned short* wp = (unsigned short*)(zb + (size_t)Npad * 64);  // 6*16384
  int* cnt      = (int*)(wp + 6 * 16384);
  int* off      = cnt + N;
  int* cursor   = off + N + 1;
  int* src_perm = cursor + N;                // [E]
  int* perm     = src_perm + E;              // [E]
  int* bsum     = perm + E;                  // [1024]
  int* bbase    = bsum + 1024;               // [1024]

  int nb = (N + 255) / 256;

  // --- CSR build + weight pack (every launch; deterministic) ---
  hipMemsetAsync(cnt, 0, (size_t)N * sizeof(int), stream);
  count_deg<<<(E + 255) / 256, 256, 0, stream>>>(dst, cnt, E);
  block_sum<<<nb, 256, 0, stream>>>(cnt, bsum, N);
  scan_bsum<<<1, 1024, 0, stream>>>(bsum, bbase, nb);
  scan_pass<<<nb, 256, 0, stream>>>(cnt, bbase, off, cursor, N);
  scatter_csr<<<(E + 255) / 256, 256, 0, stream>>>(src, dst, cursor, perm, src_perm, E);
  wpack<<<(6 * 16384 + 255) / 256, 256, 0, stream>>>(lin1_w, lin2_w, wp, 3);

  node_enc<<<N, 128, 0, stream>>>(x, node_w, node_b, h2, N);

  int ablk = (N + 3) / 4;
  for (int l = 0; l < 3; ++l) {
    hipMemsetAsync(sums, 0, 2 * H * sizeof(float), stream);
    aggr_csr<<<ablk, 256, 0, stream>>>(edge_attr, edge_w, edge_b, perm,
                                       src_perm, off, h2, zb, N);
    mlp1m<<<mblk, 256, 0, stream>>>((const unsigned short*)zb,
                                    wp + (size_t)(l * 2 + 0) * 16384,
                                    lin1_b + (size_t)l * H, t, sums, sumsq, N);
    bn_finalize<<<1, H, 0, stream>>>(sums, sumsq, bn_g + (size_t)l * H,
                                     bn_b + (size_t)l * H, scale, shift, 1.0f / N);
    bool last = (l == 2);
    if (last) hipMemsetAsync(pooled, 0, (size_t)G * H * sizeof(float), stream);
    mlp2m<<<mblk, 256, 0, stream>>>(t, scale, shift,
                                    wp + (size_t)(l * 2 + 1) * 16384,
                                    lin2_b + (size_t)l * H,
                                    last ? nullptr : (unsigned short*)h2, N,
                                    batch, last ? pooled : nullptr);
  }

  fc_kernel<<<G, 128, 0, stream>>>(pooled, fc_w, fc_b, (float*)d_out, C);
}